// Round 7
// baseline (269.583 us; speedup 1.0000x reference)
//
#include <hip/hip_runtime.h>
#include <hip/hip_bf16.h>

#define DIM 256
#define HW  1024  // 32*32

typedef __attribute__((ext_vector_type(8))) short short8;
typedef __attribute__((ext_vector_type(4))) float floatx4;
typedef __attribute__((ext_vector_type(16))) float floatx16;

__device__ inline unsigned short f2bf(float f) {
  union { float f; unsigned u; } v;
  v.f = f;
  unsigned u = v.u;
  u += 0x7fffu + ((u >> 16) & 1u);
  return (unsigned short)(u >> 16);
}

// ---------------------------------------------------------------------------
// Dtype detector: flag=1 if inputs are fp32, 0 if bf16 (see R2 notes).
// ---------------------------------------------------------------------------
__global__ void detect_kernel(const unsigned short* __restrict__ xr,
                              int* __restrict__ flag) {
  __shared__ int cnt;
  if (threadIdx.x == 0) cnt = 0;
  __syncthreads();
  int local = 0;
  for (int i = threadIdx.x; i < 8192; i += 256) {
    unsigned short u = xr[i];
    if ((u & 0x7F80u) == 0x7F80u) local++;
  }
  if (local) atomicAdd(&cnt, local);
  __syncthreads();
  if (threadIdx.x == 0) *flag = (cnt > 0) ? 1 : 0;
}

__device__ inline float ldin(const void* p, long i, int isf32) {
  if (isf32) return ((const float*)p)[i];
  union { unsigned u; float f; } v;
  v.u = ((unsigned)((const unsigned short*)p)[i]) << 16;
  return v.f;
}

// ---------------------------------------------------------------------------
// Fused prep kernel: x->bf16, conv/wp weights -> MFMA-fragment order bf16,
// biases -> fp32.
// wF layout: [tap][c8(8)][co16(16)][lane(64)][j(8)]  where
//   co = co16*16 + (lane&15), ci = c8*32 + (lane>>4)*8 + j
// ---------------------------------------------------------------------------
__device__ inline void frag_repack(const void* __restrict__ w,
                                   unsigned short* __restrict__ wF, int KK,
                                   int local_blk, int t, int isf32) {
  const int idx = local_blk * 256 + t;
  const int j    = idx & 7;
  const int lane = (idx >> 3) & 63;
  const int co16 = (idx >> 9) & 15;
  const int c8   = (idx >> 13) & 7;
  const int tap  = idx >> 16;
  const int co = (co16 << 4) | (lane & 15);
  const int ci = (c8 << 5) + ((lane >> 4) << 3) + j;
  wF[idx] = f2bf(ldin(w, (long)(co * 256 + ci) * KK + tap, isf32));
}

__global__ void prep_kernel(const void* __restrict__ x,
                            const void* __restrict__ w3,
                            const void* __restrict__ b3,
                            const void* __restrict__ w5,
                            const void* __restrict__ b5,
                            const void* __restrict__ w7,
                            const void* __restrict__ b7,
                            const void* __restrict__ wp,
                            unsigned short* __restrict__ xbf,
                            unsigned short* __restrict__ wF3,
                            unsigned short* __restrict__ wF5,
                            unsigned short* __restrict__ wF7,
                            unsigned short* __restrict__ wpF,
                            float* __restrict__ bc,  // [3][256]
                            const int* __restrict__ flag) {
  const int isf32 = *flag;
  const int bid = blockIdx.x;
  const int t = threadIdx.x;
  if (bid < 2048) {            // x -> bf16, 4 elem/thread
    const int i = (bid * 256 + t) * 4;
    if (isf32) {
      const float4 v = *(const float4*)((const float*)x + i);
      ushort4 o;
      o.x = f2bf(v.x); o.y = f2bf(v.y); o.z = f2bf(v.z); o.w = f2bf(v.w);
      *(ushort4*)(xbf + i) = o;
    } else {
      *(ushort4*)(xbf + i) = *(const ushort4*)((const unsigned short*)x + i);
    }
  } else if (bid < 2304) {
    frag_repack(w3, wF3, 1, bid - 2048, t, isf32);
  } else if (bid < 4608) {
    frag_repack(w5, wF5, 9, bid - 2304, t, isf32);
  } else if (bid < 11008) {
    frag_repack(w7, wF7, 25, bid - 4608, t, isf32);
  } else if (bid < 11264) {
    frag_repack(wp, wpF, 1, bid - 11008, t, isf32);
  } else {                     // biases: 768 elements
#pragma unroll
    for (int r = 0; r < 3; ++r) {
      const int i = r * 256 + t;
      const void* src = (i < 256) ? b3 : (i < 512) ? b5 : b7;
      bc[i] = ldin(src, i & 255, isf32);
    }
  }
}

// ---------------------------------------------------------------------------
// MFMA implicit-GEMM conv, SAME padding, stride 1, bf16 in / bf16 out.
// R7: XCD-aware swizzle (co_group = bid&3 -> each XCD's L2 holds one 1/4
// weight slice + half of x, no thrash) + __launch_bounds__(256,2) + explicit
// one-tap-ahead register prefetch of A(LDS)/B(global) fragments.
//   xbf : [8][32][32][256] bf16 NHWC;  wF : fragment order (see prep)
// Attention coords (R2-verified): slab=(b<<4)+(co>>4),
//   m = (co&15)*64 + (n>>4), d = n&15
//   out : TSTORE==0 -> QK rows [slab][m][16d]: (slab<<14)+((co&15)<<10)+n
//         TSTORE==1 -> V^T     [slab][d][1024m]:
//                      (slab<<14)+((n&15)<<10)+((co&15)<<6)+(n>>4)
// Block: 256 thr = 4 waves; tile 64 pos (2 rows x 32 cols) x 64 co.
// ---------------------------------------------------------------------------
template <int KS, int TSTORE>
__global__ __launch_bounds__(256, 2) void conv_mfma_kernel(
    const unsigned short* __restrict__ xbf,
    const unsigned short* __restrict__ wF,
    const float* __restrict__ bias, unsigned short* __restrict__ out) {
  constexpr int P = KS / 2;
  constexpr int TAPS = KS * KS;
  constexpr int HR = 2 + 2 * P;    // halo rows
  constexpr int WC = 32 + 2 * P;   // halo cols
  constexpr int CELLS = HR * WC;
  constexpr int LOADS = CELLS * 4; // 4 x uint4 (8 bf16) per cell
  constexpr int ROUNDS = (LOADS + 255) / 256;
  __shared__ unsigned short Xs[CELLS * 40];  // [cell][32ci pad40]
  const int t   = threadIdx.x;
  const int bid = blockIdx.x;
  const int co0 = (bid & 3) << 6;      // XCD-local co-group (bid%8 fixes it)
  const int m0  = (bid >> 2) << 6;
  const int b   = m0 >> 10;
  const int n0  = m0 & 1023;
  const int r0  = n0 >> 5;             // first of 2 image rows
  const int wv   = t >> 6;
  const int lane = t & 63;
  const int wm = (wv & 1) << 5;
  const int wn = (wv >> 1) << 5;
  const int l15  = lane & 15;
  const int quad = lane >> 4;
  const int rbase = wm >> 5;           // 0 or 1
  const int cogb  = (co0 >> 4) + (wn >> 4);

  floatx4 acc[2][2] = {};

  for (int c8 = 0; c8 < 8; ++c8) {
    __syncthreads();  // all waves done reading previous chunk's Xs
#pragma unroll
    for (int rr = 0; rr < ROUNDS; ++rr) {
      const int id = rr * 256 + t;
      if (ROUNDS * 256 == LOADS || id < LOADS) {
        const int cell = id >> 2;
        const int part = id & 3;
        const int hr = cell / WC;
        const int wc = cell - hr * WC;
        const int xr = r0 + hr - P;
        const int xc = wc - P;
        uint4 v = make_uint4(0, 0, 0, 0);
        if (((unsigned)xr < 32u) && ((unsigned)xc < 32u))
          v = *(const uint4*)&xbf[(((b * 32 + xr) * 32 + xc) << 8) +
                                  (c8 << 5) + (part << 3)];
        *(uint4*)&Xs[cell * 40 + (part << 3)] = v;
      }
    }
    __syncthreads();

    // ---- tap loop, one-tap-ahead register prefetch ----
    short8 cb0, cb1, ca0, ca1;
    {
      const unsigned short* wptr =
          &wF[((c8 << 4) + cogb) * 512 + (lane << 3)];
      cb0 = *(const short8*)wptr;
      cb1 = *(const short8*)(wptr + 512);
      const unsigned short* xs =
          &Xs[(rbase * WC + l15) * 40 + (quad << 3)];
      ca0 = *(const short8*)xs;
      ca1 = *(const short8*)(xs + 16 * 40);
    }
#pragma unroll
    for (int tap = 0; tap < TAPS; ++tap) {
      short8 nb0 = {}, nb1 = {}, na0 = {}, na1 = {};
      if (tap + 1 < TAPS) {  // constant-folded per unrolled iteration
        const int nt = tap + 1;
        const unsigned short* wptr =
            &wF[((((nt << 3) + c8) << 4) + cogb) * 512 + (lane << 3)];
        nb0 = *(const short8*)wptr;
        nb1 = *(const short8*)(wptr + 512);
        const int kh = nt / KS, kw = nt % KS;
        const unsigned short* xs =
            &Xs[((rbase + kh) * WC + l15 + kw) * 40 + (quad << 3)];
        na0 = *(const short8*)xs;
        na1 = *(const short8*)(xs + 16 * 40);
      }
      acc[0][0] = __builtin_amdgcn_mfma_f32_16x16x32_bf16(ca0, cb0,
                                                          acc[0][0], 0, 0, 0);
      acc[0][1] = __builtin_amdgcn_mfma_f32_16x16x32_bf16(ca0, cb1,
                                                          acc[0][1], 0, 0, 0);
      acc[1][0] = __builtin_amdgcn_mfma_f32_16x16x32_bf16(ca1, cb0,
                                                          acc[1][0], 0, 0, 0);
      acc[1][1] = __builtin_amdgcn_mfma_f32_16x16x32_bf16(ca1, cb1,
                                                          acc[1][1], 0, 0, 0);
      cb0 = nb0; cb1 = nb1; ca0 = na0; ca1 = na1;
    }
  }
  // epilogue: C/D layout col=l15 (co), row=quad*4+reg (position) [R5-verified]
#pragma unroll
  for (int mi = 0; mi < 2; ++mi) {
#pragma unroll
    for (int ni = 0; ni < 2; ++ni) {
      const int co = co0 + wn + (ni << 4) + l15;
      const float bj = bias[co];
      const int nb = n0 + wm + (mi << 4) + (quad << 2);
      const int slab = (b << 4) + (co >> 4);
      const int clo = co & 15;
      floatx4 a = acc[mi][ni];
      if (TSTORE == 0) {
        ushort4 pk;
        pk.x = f2bf(a[0] + bj); pk.y = f2bf(a[1] + bj);
        pk.z = f2bf(a[2] + bj); pk.w = f2bf(a[3] + bj);
        *(ushort4*)&out[(slab << 14) + (clo << 10) + nb] = pk;
      } else {
        const int base = (slab << 14) + (clo << 6);
#pragma unroll
        for (int i = 0; i < 4; ++i) {
          const int n = nb + i;
          out[base + ((n & 15) << 10) + (n >> 4)] = f2bf(a[i] + bj);
        }
      }
    }
  }
}

// ---------------------------------------------------------------------------
// MFMA attention per (b,h) slab: softmax(Q K^T * 0.25) V.  [R5-verified]
//   qg, kg : bf16 [slab][1024 m][16 d];  vg : bf16 [slab][16 d][1024 m]
//   out2   : bf16 [8][1024 m][256], c = h*16+d
// ---------------------------------------------------------------------------
__global__ __launch_bounds__(256) void attn_mfma_kernel(
    const unsigned short* __restrict__ qg,
    const unsigned short* __restrict__ kg,
    const unsigned short* __restrict__ vg,
    unsigned short* __restrict__ out2) {
  __shared__ __align__(16) unsigned short Kc[16384];     // [key][16]
  __shared__ __align__(16) unsigned short Vt[16][1032];  // [d][key], padded
  __shared__ __align__(16) unsigned short Pb[4][32][40]; // per-wave P
  __shared__ float lb[4][32];
  const int t    = threadIdx.x;
  const int w    = t >> 6;
  const int lane = t & 63;
  const int slab = blockIdx.x >> 3;
  const int rb   = blockIdx.x & 7;
  const int b = slab >> 4;
  const int h = slab & 15;
  const int l31  = lane & 31;
  const int hl   = lane >> 5;
  const int l15  = lane & 15;
  const int quad = lane >> 4;

#pragma unroll
  for (int j = 0; j < 8; ++j) {
    const int id = (j << 8) + t;
    const int e  = id << 3;
    *(uint4*)&Kc[e] = *(const uint4*)&kg[(slab << 14) + e];
    const int d = e >> 10, ky = e & 1023;
    *(uint4*)&Vt[d][ky] = *(const uint4*)&vg[(slab << 14) + e];
  }

  const int row0 = (rb << 7) + (w << 5);
  const short8 qa =
      *(const short8*)&qg[(slab << 14) + ((row0 + l31) << 4) + (hl << 3)];

  float lsum[16] = {};
  floatx4 acco[2] = {};
  const float sc = 0.25f * 1.4426950408889634f;

  __syncthreads();

  for (int kc = 0; kc < 1024; kc += 32) {
    const short8 kb = *(const short8*)&Kc[((kc + l31) << 4) + (hl << 3)];
    floatx16 s = {};
    s = __builtin_amdgcn_mfma_f32_32x32x16_bf16(qa, kb, s, 0, 0, 0);
#pragma unroll
    for (int r = 0; r < 16; ++r) {
      const float e = exp2f(s[r] * sc);
      lsum[r] += e;
      const int row = (r & 3) + ((r >> 2) << 3) + (hl << 2);
      Pb[w][row][l31] = f2bf(e);
    }
    const short8 vb = *(const short8*)&Vt[l15][kc + (quad << 3)];
#pragma unroll
    for (int tt = 0; tt < 2; ++tt) {
      const short8 pa = *(const short8*)&Pb[w][(tt << 4) + l15][quad << 3];
      acco[tt] =
          __builtin_amdgcn_mfma_f32_16x16x32_bf16(pa, vb, acco[tt], 0, 0, 0);
    }
  }

#pragma unroll
  for (int r = 0; r < 16; ++r) {
    float lv = lsum[r];
    lv += __shfl_xor(lv, 1, 64);
    lv += __shfl_xor(lv, 2, 64);
    lv += __shfl_xor(lv, 4, 64);
    lv += __shfl_xor(lv, 8, 64);
    lv += __shfl_xor(lv, 16, 64);
    lsum[r] = lv;
  }
  {
    const int rr = l31;
    if (((rr >> 2) & 1) == hl) {
      const int reg = (rr & 3) + ((rr >> 3) << 2);
      lb[w][rr] = 1.0f / lsum[reg];
    }
  }
#pragma unroll
  for (int tt = 0; tt < 2; ++tt) {
#pragma unroll
    for (int r = 0; r < 4; ++r) {
      const int nloc = (tt << 4) + (quad << 2) + r;
      const float val = acco[tt][r] * lb[w][nloc];
      const int n = row0 + nloc;
      out2[(((b << 10) + n) << 8) + (h << 4) + l15] = f2bf(val);
    }
  }
}

// ---------------------------------------------------------------------------
// Final linear, MFMA bf16: y[m][co] = sum_ci o2b[m][ci] * wp[co][ci].
// ---------------------------------------------------------------------------
__global__ __launch_bounds__(256) void linear_mfma_kernel(
    const unsigned short* __restrict__ inp,  // bf16 [8192][256]
    const unsigned short* __restrict__ wpF,  // fragment order
    void* __restrict__ out, const int* __restrict__ flag) {
  __shared__ unsigned short As[64 * 40];
  const int isf32 = *flag;
  const int t   = threadIdx.x;
  const int m0  = blockIdx.x << 6;
  const int co0 = blockIdx.y << 6;
  const int wv   = t >> 6;
  const int lane = t & 63;
  const int wm = (wv & 1) << 5;
  const int wn = (wv >> 1) << 5;
  const int l15  = lane & 15;
  const int quad = lane >> 4;
  const int cogb = (co0 >> 4) + (wn >> 4);
  const int rowS = t >> 2;
  const int partS = t & 3;

  floatx4 acc[2][2] = {};

  for (int c8 = 0; c8 < 8; ++c8) {
    const uint4 v = *(const uint4*)&inp[((m0 + rowS) << 8) + (c8 << 5) +
                                        (partS << 3)];
    __syncthreads();
    *(uint4*)&As[rowS * 40 + (partS << 3)] = v;
    __syncthreads();
    const unsigned short* wptr = &wpF[(((c8 << 4) + cogb) << 9) + (lane << 3)];
    const short8 bfr0 = *(const short8*)wptr;
    const short8 bfr1 = *(const short8*)(wptr + 512);
    const unsigned short* xs = &As[(wm + l15) * 40 + (quad << 3)];
    const short8 afr0 = *(const short8*)xs;
    const short8 afr1 = *(const short8*)(xs + 16 * 40);
    acc[0][0] = __builtin_amdgcn_mfma_f32_16x16x32_bf16(afr0, bfr0,
                                                        acc[0][0], 0, 0, 0);
    acc[0][1] = __builtin_amdgcn_mfma_f32_16x16x32_bf16(afr0, bfr1,
                                                        acc[0][1], 0, 0, 0);
    acc[1][0] = __builtin_amdgcn_mfma_f32_16x16x32_bf16(afr1, bfr0,
                                                        acc[1][0], 0, 0, 0);
    acc[1][1] = __builtin_amdgcn_mfma_f32_16x16x32_bf16(afr1, bfr1,
                                                        acc[1][1], 0, 0, 0);
  }
#pragma unroll
  for (int mi = 0; mi < 2; ++mi) {
#pragma unroll
    for (int ni = 0; ni < 2; ++ni) {
      const int co = co0 + wn + (ni << 4) + l15;
      const int mb = m0 + wm + (mi << 4) + (quad << 2);
      floatx4 a = acc[mi][ni];
      if (!isf32) {
        unsigned short* o16 = (unsigned short*)out;
#pragma unroll
        for (int r = 0; r < 4; ++r) o16[(mb + r) * 256 + co] = f2bf(a[r]);
      } else {
        float* o32 = (float*)out;
#pragma unroll
        for (int r = 0; r < 4; ++r) o32[(mb + r) * 256 + co] = a[r];
      }
    }
  }
}

// ---------------------------------------------------------------------------
extern "C" void kernel_launch(void* const* d_in, const int* in_sizes, int n_in,
                              void* d_out, int out_size, void* d_ws,
                              size_t ws_size, hipStream_t stream) {
  const void* x  = d_in[0];
  const void* w3 = d_in[1];
  const void* b3 = d_in[2];
  const void* w5 = d_in[3];
  const void* b5 = d_in[4];
  const void* w7 = d_in[5];
  const void* b7 = d_in[6];
  const void* wp = d_in[7];

  char* p = (char*)d_ws;
  int* flag = (int*)p;                       p += 256;
  unsigned short* xbf = (unsigned short*)p;  p += 4u * 1024 * 1024;
  unsigned short* wF3 = (unsigned short*)p;  p += 131072;
  unsigned short* wF5 = (unsigned short*)p;  p += 1179648;
  unsigned short* wF7 = (unsigned short*)p;  p += 3276800;
  unsigned short* wpF = (unsigned short*)p;  p += 131072;
  float* bc = (float*)p;                     p += 4096;     // [3][256]
  unsigned short* qc  = (unsigned short*)p;  p += 4194304;  // bf16 QK rows
  unsigned short* kT  = (unsigned short*)p;  p += 4194304;  // bf16 QK rows
  unsigned short* vT  = (unsigned short*)p;  p += 4194304;  // bf16 V^T
  unsigned short* o2b = (unsigned short*)p;  p += 4194304;  // bf16 [8192][256]

  detect_kernel<<<1, 256, 0, stream>>>((const unsigned short*)x, flag);

  prep_kernel<<<11265, 256, 0, stream>>>(x, w3, b3, w5, b5, w7, b7, wp, xbf,
                                         wF3, wF5, wF7, wpF, bc, flag);

  conv_mfma_kernel<1, 0><<<512, 256, 0, stream>>>(xbf, wF3, bc, qc);        // q
  conv_mfma_kernel<3, 1><<<512, 256, 0, stream>>>(xbf, wF5, bc + 256, vT);  // v
  conv_mfma_kernel<5, 0><<<512, 256, 0, stream>>>(xbf, wF7, bc + 512, kT);  // k

  attn_mfma_kernel<<<1024, 256, 0, stream>>>(qc, kT, vT, o2b);

  dim3 lg(128, 4);
  linear_mfma_kernel<<<lg, 256, 0, stream>>>(o2b, wpF, d_out, flag);
}